// Round 10
// baseline (219.186 us; speedup 1.0000x reference)
//
#include <hip/hip_runtime.h>

typedef __attribute__((ext_vector_type(8))) short bf16x8;
typedef __attribute__((ext_vector_type(4))) float f32x4;

#define N_NODES 10000
#define N_EDGES 160000
#define FDIM    512
#define ELL     64
// gemm tile
#define BM 64
#define BN 128
#define BK 64
#define TM 157              // ceil(10000/64)
#define NGEMM (TM * 4)      // 628
#define NSCAT 625           // 625*256 = 160000
#define NTR1  256           // W1: 256 tiles of 32x32
#define NTR23 512           // W2+W3 transpose tails in gemm1 grid
#define NZERO 40            // 40*256 >= 10000
// agg slicing
#define SLICES 4
#define SLW 128             // feats per slice (2.5 MB slice -> L2-resident)
#define SLB 2500            // node-group blocks per slice (4 nodes/block)

__device__ __forceinline__ float bf2f(unsigned int u) {
    union { unsigned int i; float f; } v; v.i = u << 16; return v.f;
}
__device__ __forceinline__ unsigned short f2bf(float f) {
    union { float f; unsigned int u; } v; v.f = f;
    unsigned int u = v.u;
    unsigned int r = u + 0x7fffu + ((u >> 16) & 1u);
    return (unsigned short)(r >> 16);
}
__device__ __forceinline__ void gload_lds16(const void* g, void* l) {
    __builtin_amdgcn_global_load_lds(
        (const __attribute__((address_space(1))) unsigned int*)g,
        (__attribute__((address_space(3))) unsigned int*)l, 16, 0, 0);
}
__device__ __forceinline__ int wave_is_f32(const unsigned int* w) {
    unsigned int v = w[(size_t)(threadIdx.x & 63) * 1000];
    unsigned int ex = (v >> 7) & 0xFFu;
    unsigned long long inb = __ballot(ex >= 100u && ex <= 140u);
    return (__popcll(inb) >= 48) ? 0 : 1;
}

// ---- shared transpose-tile helper (32x32 tile t of matrix W -> out) -----------
__device__ __forceinline__ void tr_tile(const void* W, unsigned short* outp,
                                        int t, int tid, void* ldsbuf) {
    unsigned short (*tile)[33] = (unsigned short (*)[33])ldsbuf;
    int ff32 = wave_is_f32((const unsigned int*)W);
    int tx = tid & 31, ty = tid >> 5;              // 32 x 8
    int xcol = (t & 15) * 32 + tx;
    int y0 = (t >> 4) * 32 + ty;
    #pragma unroll
    for (int j = 0; j < 32; j += 8) {
        int idx = (y0 + j) * FDIM + xcol;
        tile[ty + j][tx] = ff32 ? f2bf(((const float*)W)[idx])
                                : ((const unsigned short*)W)[idx];
    }
    __syncthreads();
    int x2 = (t >> 4) * 32 + tx;
    int y2 = (t & 15) * 32 + ty;
    #pragma unroll
    for (int j = 0; j < 32; j += 8)
        outp[(y2 + j) * FDIM + x2] = tile[tx][ty + j];
}

// ---------------- N1: transpose W1 || zero cnt || flags ------------------------
__global__ __launch_bounds__(256) void prep_v10(
        const void* __restrict__ x, const void* __restrict__ ei,
        const void* __restrict__ W1, unsigned short* __restrict__ Wt,
        int* __restrict__ cnt, int* __restrict__ flags) {
    __shared__ unsigned short tile[32][33];
    int b = blockIdx.x, tid = threadIdx.x;
    if (b < NTR1) {
        tr_tile(W1, Wt, b, tid, tile);
    } else if (b < NTR1 + NZERO) {
        int i = (b - NTR1) * 256 + tid;
        if (i < N_NODES) cnt[i] = 0;
    } else {
        if (tid < 64) {
            const unsigned long long* e64 = (const unsigned long long*)ei;
            unsigned long long v = e64[(size_t)tid * 2500];
            unsigned long long big = __ballot(v > 0xFFFFFFFFull);
            const unsigned int* xw = (const unsigned int*)x;
            unsigned int w = xw[(size_t)tid * 1000];
            unsigned int ex = (w >> 7) & 0xFFu;
            unsigned long long inb = __ballot(ex >= 100u && ex <= 140u);
            if (tid == 0) {
                flags[0] = (big == 0ull) ? 1 : 0;          // int64?
                flags[1] = (__popcll(inb) >= 48) ? 0 : 1;  // f32?
            }
        }
    }
}

// ---------------- N2/N4/N6: swizzled MFMA GEMM (+opt scatter/transpose tails) --
__global__ __launch_bounds__(256) void gemm_v10(
        const void* __restrict__ Ap, const unsigned short* __restrict__ Bt,
        unsigned short* __restrict__ C, int a_ext,
        const int* __restrict__ flags, const void* __restrict__ ei,
        int* __restrict__ cnt, int* __restrict__ ell,
        const void* __restrict__ W2, const void* __restrict__ W3,
        unsigned short* __restrict__ Wt23) {
    __shared__ unsigned short As[BM * BK];
    __shared__ unsigned short Bs[BN * BK];
    if (blockIdx.x >= NGEMM) {
        int tb = blockIdx.x - NGEMM;
        if (tb < NSCAT) {
            // ---- ELL scatter (slot = running count) ----
            int e = tb * 256 + threadIdx.x;
            if (e < N_EDGES) {
                int r, c;
                if (flags[0]) {
                    r = (int)((const long long*)ei)[e];
                    c = (int)((const long long*)ei)[N_EDGES + e];
                } else {
                    r = ((const int*)ei)[e];
                    c = ((const int*)ei)[N_EDGES + e];
                }
                int slot = atomicAdd(&cnt[c], 1);
                if (slot < ELL) ell[(size_t)c * ELL + slot] = r;
            }
        } else {
            // ---- transpose W2/W3 (used 2 dispatches later) ----
            int t = tb - NSCAT;        // 0..511
            int z = t >> 8;            // 0 -> W2, 1 -> W3
            tr_tile(z ? W3 : W2, Wt23 + (size_t)z * FDIM * FDIM, t & 255,
                    threadIdx.x, As);
        }
        return;
    }
    const int K = FDIM;
    const int af32 = a_ext ? flags[1] : 0;
    const int tid = threadIdx.x;
    const int t = blockIdx.x;
    const int bm = (t % TM) * BM, bn = (t / TM) * BN;
    const int lane = tid & 63, wv = tid >> 6;
    const int wm = (wv >> 1) * 32, wn = (wv & 1) * 64;
    const int lrow = lane & 15;
    const int tsl = lane >> 4;                        // 16B slot base (0..3)
    const int ksw = (lane & 7) ^ ((lane >> 3) & 7);   // swizzled stage k-slot
    const unsigned short* Abf = (const unsigned short*)Ap;
    f32x4 acc[2][4] = {};

    for (int k0 = 0; k0 < K; k0 += BK) {
        if (!af32) {
            #pragma unroll
            for (int j = 0; j < 2; ++j) {                 // A: 64 rows
                int r0 = wv * 16 + j * 8;
                int arow = bm + r0 + (lane >> 3);
                if (arow >= N_NODES) arow = N_NODES - 1;  // clamp: discarded
                gload_lds16(Abf + (size_t)arow * K + k0 + ksw * 8, &As[r0 * BK]);
            }
            #pragma unroll
            for (int j = 0; j < 4; ++j) {                 // B: 128 rows
                int r0 = wv * 32 + j * 8;
                gload_lds16(Bt + (size_t)(bn + r0 + (lane >> 3)) * K + k0 + ksw * 8,
                            &Bs[r0 * BK]);
            }
        } else {
            #pragma unroll
            for (int j = 0; j < 4; ++j) {
                int r0 = wv * 32 + j * 8;
                gload_lds16(Bt + (size_t)(bn + r0 + (lane >> 3)) * K + k0 + ksw * 8,
                            &Bs[r0 * BK]);
            }
            #pragma unroll
            for (int i = 0; i < 2; ++i) {                 // A f32 fallback
                int c = tid + i * 256;
                int row = c >> 3, sl = c & 7;
                int grow = bm + row;
                bf16x8 va = {};
                if (grow < N_NODES) {
                    const float* Af = (const float*)Ap + (size_t)grow * K + k0 + sl * 8;
                    f32x4 lo = *(const f32x4*)Af;
                    f32x4 hi = *(const f32x4*)(Af + 4);
                    #pragma unroll
                    for (int jj = 0; jj < 4; ++jj) {
                        va[jj]     = (short)f2bf(lo[jj]);
                        va[4 + jj] = (short)f2bf(hi[jj]);
                    }
                }
                *(bf16x8*)(&As[row * BK + ((sl ^ (row & 7)) * 8)]) = va;
            }
        }
        __syncthreads();
        #pragma unroll
        for (int half = 0; half < 2; ++half) {
            int ts = half * 4 + tsl;
            bf16x8 af[2], bfr[4];
            #pragma unroll
            for (int f = 0; f < 2; ++f) {
                int row = wm + f * 16 + lrow;
                af[f] = *(const bf16x8*)(&As[row * BK + ((ts ^ (lrow & 7)) * 8)]);
            }
            #pragma unroll
            for (int f = 0; f < 4; ++f) {
                int row = wn + f * 16 + lrow;
                bfr[f] = *(const bf16x8*)(&Bs[row * BK + ((ts ^ (lrow & 7)) * 8)]);
            }
            #pragma unroll
            for (int fm = 0; fm < 2; ++fm)
                #pragma unroll
                for (int fn = 0; fn < 4; ++fn)
                    acc[fm][fn] = __builtin_amdgcn_mfma_f32_16x16x32_bf16(
                        af[fm], bfr[fn], acc[fm][fn], 0, 0, 0);
        }
        __syncthreads();
    }

    int crow = (lane >> 4) * 4;
    int ccol = lane & 15;
    #pragma unroll
    for (int fm = 0; fm < 2; ++fm)
        #pragma unroll
        for (int fn = 0; fn < 4; ++fn)
            #pragma unroll
            for (int r = 0; r < 4; ++r) {
                int row = bm + wm + fm * 16 + crow + r;
                if (row < N_NODES)
                    C[(size_t)row * FDIM + bn + wn + fn * 16 + ccol] =
                        f2bf(acc[fm][fn][r]);
            }
}

// ---------------- N3: agg pass 1 — shfl norms, builds packed ell2 --------------
// Slice-major grid; wave = 1 node; lane owns 2 feats (uint).
__global__ __launch_bounds__(256) void agg_build_v10(
        const unsigned short* __restrict__ gin, const void* __restrict__ bias,
        const int* __restrict__ cnt, const int* __restrict__ ell,
        int2* __restrict__ ell2, void* __restrict__ out,
        const int* __restrict__ flags) {
    const int wv = threadIdx.x >> 6, lane = threadIdx.x & 63;
    const int slice = blockIdx.x / SLB;
    const int i = (blockIdx.x % SLB) * 4 + wv;
    const int fu = slice * (SLW / 2) + lane;
    const unsigned int* g32 = (const unsigned int*)gin;
    int ci = cnt[i];
    int re = (ci > ELL) ? ELL : ci;
    const int* ep = ell + (size_t)i * ELL;
    int   srcl = (lane < re) ? ep[lane] : 0;
    int   cl   = (lane < re) ? cnt[srcl] : 0;
    float wl   = rsqrtf((float)(cl + 1) * (float)(ci + 1));
    if (slice == 0 && lane < re) {            // materialize packed (src, norm)
        int2 pk; pk.x = srcl; pk.y = __float_as_int(wl);
        ell2[(size_t)i * ELL + lane] = pk;
    }
    float a0 = 0.f, a1 = 0.f;
    int j = 0;
    for (; j + 8 <= re; j += 8) {
        int s0 = __shfl(srcl, j);     float w0 = __shfl(wl, j);
        int s1 = __shfl(srcl, j + 1); float w1 = __shfl(wl, j + 1);
        int s2 = __shfl(srcl, j + 2); float w2 = __shfl(wl, j + 2);
        int s3 = __shfl(srcl, j + 3); float w3 = __shfl(wl, j + 3);
        int s4 = __shfl(srcl, j + 4); float w4 = __shfl(wl, j + 4);
        int s5 = __shfl(srcl, j + 5); float w5 = __shfl(wl, j + 5);
        int s6 = __shfl(srcl, j + 6); float w6 = __shfl(wl, j + 6);
        int s7 = __shfl(srcl, j + 7); float w7 = __shfl(wl, j + 7);
        unsigned int v0 = g32[(size_t)s0 * 256 + fu];
        unsigned int v1 = g32[(size_t)s1 * 256 + fu];
        unsigned int v2 = g32[(size_t)s2 * 256 + fu];
        unsigned int v3 = g32[(size_t)s3 * 256 + fu];
        unsigned int v4 = g32[(size_t)s4 * 256 + fu];
        unsigned int v5 = g32[(size_t)s5 * 256 + fu];
        unsigned int v6 = g32[(size_t)s6 * 256 + fu];
        unsigned int v7 = g32[(size_t)s7 * 256 + fu];
        a0 += w0 * bf2f(v0 & 0xffffu); a1 += w0 * bf2f(v0 >> 16);
        a0 += w1 * bf2f(v1 & 0xffffu); a1 += w1 * bf2f(v1 >> 16);
        a0 += w2 * bf2f(v2 & 0xffffu); a1 += w2 * bf2f(v2 >> 16);
        a0 += w3 * bf2f(v3 & 0xffffu); a1 += w3 * bf2f(v3 >> 16);
        a0 += w4 * bf2f(v4 & 0xffffu); a1 += w4 * bf2f(v4 >> 16);
        a0 += w5 * bf2f(v5 & 0xffffu); a1 += w5 * bf2f(v5 >> 16);
        a0 += w6 * bf2f(v6 & 0xffffu); a1 += w6 * bf2f(v6 >> 16);
        a0 += w7 * bf2f(v7 & 0xffffu); a1 += w7 * bf2f(v7 >> 16);
    }
    for (; j < re; ++j) {
        int s = __shfl(srcl, j); float w = __shfl(wl, j);
        unsigned int v = g32[(size_t)s * 256 + fu];
        a0 += w * bf2f(v & 0xffffu); a1 += w * bf2f(v >> 16);
    }
    float wself = 1.0f / (float)(ci + 1);
    unsigned int vs = g32[(size_t)i * 256 + fu];
    a0 += wself * bf2f(vs & 0xffffu); a1 += wself * bf2f(vs >> 16);
    if (flags[1]) {
        const float* B = (const float*)bias + fu * 2;
        a0 += B[0]; a1 += B[1];
    } else {
        unsigned int bb = ((const unsigned int*)bias)[fu];
        a0 += bf2f(bb & 0xffffu); a1 += bf2f(bb >> 16);
    }
    a0 = fmaxf(a0, 0.f); a1 = fmaxf(a1, 0.f);     // layer-1 relu
    unsigned int o = (unsigned int)f2bf(a0) | ((unsigned int)f2bf(a1) << 16);
    ((unsigned int*)out)[(size_t)i * 256 + fu] = o;
}

// ---------------- N5/N7: agg via uniform packed ell2 (no shfl, no cnt gather) --
__global__ __launch_bounds__(256) void agg_use_v10(
        const unsigned short* __restrict__ gin, const void* __restrict__ bias,
        const int* __restrict__ cnt, const int2* __restrict__ ell2,
        void* __restrict__ out, int relu, int out_ext,
        const int* __restrict__ flags) {
    const int wv = threadIdx.x >> 6, lane = threadIdx.x & 63;
    const int slice = blockIdx.x / SLB;
    const int i = (blockIdx.x % SLB) * 4 + wv;
    const int fu = slice * (SLW / 2) + lane;
    const unsigned int* g32 = (const unsigned int*)gin;
    int ci = cnt[i];
    int re = (ci > ELL) ? ELL : ci;
    const int2* ep = ell2 + (size_t)i * ELL;
    float a0 = 0.f, a1 = 0.f;
    int j = 0;
    for (; j + 8 <= re; j += 8) {
        int2 p0 = ep[j],     p1 = ep[j + 1], p2 = ep[j + 2], p3 = ep[j + 3];
        int2 p4 = ep[j + 4], p5 = ep[j + 5], p6 = ep[j + 6], p7 = ep[j + 7];
        unsigned int v0 = g32[(size_t)p0.x * 256 + fu];
        unsigned int v1 = g32[(size_t)p1.x * 256 + fu];
        unsigned int v2 = g32[(size_t)p2.x * 256 + fu];
        unsigned int v3 = g32[(size_t)p3.x * 256 + fu];
        unsigned int v4 = g32[(size_t)p4.x * 256 + fu];
        unsigned int v5 = g32[(size_t)p5.x * 256 + fu];
        unsigned int v6 = g32[(size_t)p6.x * 256 + fu];
        unsigned int v7 = g32[(size_t)p7.x * 256 + fu];
        float w0 = __int_as_float(p0.y), w1 = __int_as_float(p1.y);
        float w2 = __int_as_float(p2.y), w3 = __int_as_float(p3.y);
        float w4 = __int_as_float(p4.y), w5 = __int_as_float(p5.y);
        float w6 = __int_as_float(p6.y), w7 = __int_as_float(p7.y);
        a0 += w0 * bf2f(v0 & 0xffffu); a1 += w0 * bf2f(v0 >> 16);
        a0 += w1 * bf2f(v1 & 0xffffu); a1 += w1 * bf2f(v1 >> 16);
        a0 += w2 * bf2f(v2 & 0xffffu); a1 += w2 * bf2f(v2 >> 16);
        a0 += w3 * bf2f(v3 & 0xffffu); a1 += w3 * bf2f(v3 >> 16);
        a0 += w4 * bf2f(v4 & 0xffffu); a1 += w4 * bf2f(v4 >> 16);
        a0 += w5 * bf2f(v5 & 0xffffu); a1 += w5 * bf2f(v5 >> 16);
        a0 += w6 * bf2f(v6 & 0xffffu); a1 += w6 * bf2f(v6 >> 16);
        a0 += w7 * bf2f(v7 & 0xffffu); a1 += w7 * bf2f(v7 >> 16);
    }
    for (; j < re; ++j) {
        int2 pp = ep[j];
        float w = __int_as_float(pp.y);
        unsigned int v = g32[(size_t)pp.x * 256 + fu];
        a0 += w * bf2f(v & 0xffffu); a1 += w * bf2f(v >> 16);
    }
    float wself = 1.0f / (float)(ci + 1);
    unsigned int vs = g32[(size_t)i * 256 + fu];
    a0 += wself * bf2f(vs & 0xffffu); a1 += wself * bf2f(vs >> 16);
    int ff32 = flags[1];
    if (ff32) {
        const float* B = (const float*)bias + fu * 2;
        a0 += B[0]; a1 += B[1];
    } else {
        unsigned int bb = ((const unsigned int*)bias)[fu];
        a0 += bf2f(bb & 0xffffu); a1 += bf2f(bb >> 16);
    }
    if (relu) { a0 = fmaxf(a0, 0.f); a1 = fmaxf(a1, 0.f); }
    if (out_ext && ff32) {
        float2 o = {a0, a1};
        *(float2*)((float*)out + (size_t)i * FDIM + fu * 2) = o;
    } else {
        unsigned int o = (unsigned int)f2bf(a0) | ((unsigned int)f2bf(a1) << 16);
        ((unsigned int*)out)[(size_t)i * 256 + fu] = o;
    }
}

// ---------------- launcher ------------------------------------------------------
extern "C" void kernel_launch(void* const* d_in, const int* in_sizes, int n_in,
                              void* d_out, int out_size, void* d_ws, size_t ws_size,
                              hipStream_t stream) {
    (void)in_sizes; (void)n_in; (void)out_size; (void)ws_size;
    const void* x  = d_in[0];
    const void* ei = d_in[1];
    const void* W1 = d_in[2];
    const void* b1 = d_in[3];
    const void* W2 = d_in[4];
    const void* b2 = d_in[5];
    const void* W3 = d_in[6];
    const void* b3 = d_in[7];

    char* p = (char*)d_ws;
    auto alloc = [&](size_t bytes) -> void* {
        void* r = (void*)p;
        p += (bytes + 255) & ~(size_t)255;
        return r;
    };
    int*  flags = (int*) alloc(16);
    int*  cnt   = (int*) alloc((size_t)N_NODES * 4);
    int*  ell   = (int*) alloc((size_t)N_NODES * ELL * 4);
    int2* ell2  = (int2*)alloc((size_t)N_NODES * ELL * 8);
    unsigned short* Wt = (unsigned short*)alloc((size_t)3 * FDIM * FDIM * 2);
    unsigned short* g  = (unsigned short*)alloc((size_t)N_NODES * FDIM * 2);
    // ws use ~19.5 MB

    unsigned short* Wt1 = Wt;
    unsigned short* Wt2 = Wt + (size_t)FDIM * FDIM;
    unsigned short* Wt3 = Wt + (size_t)2 * FDIM * FDIM;
    unsigned short* h   = (unsigned short*)d_out;       // bf16 scratch in d_out

    // N1: transpose W1 + zero cnt + flags
    prep_v10<<<NTR1 + NZERO + 1, 256, 0, stream>>>(x, ei, W1, Wt1, cnt, flags);
    // N2: g = x*W1  (+ ELL scatter, + W2/W3 transpose tails)
    gemm_v10<<<NGEMM + NSCAT + NTR23, 256, 0, stream>>>(
        x, Wt1, g, 1, flags, ei, cnt, ell, W2, W3, Wt2);
    // N3: h = relu(agg(g) + b1); builds ell2
    agg_build_v10<<<SLICES * SLB, 256, 0, stream>>>(g, b1, cnt, ell, ell2, h, flags);
    // N4: g = h*W2
    gemm_v10<<<NGEMM, 256, 0, stream>>>(h, Wt2, g, 0, flags, ei, cnt, ell,
                                        W2, W3, Wt2);
    // N5: h = relu(agg(g) + b2)
    agg_use_v10<<<SLICES * SLB, 256, 0, stream>>>(g, b2, cnt, ell2, h, 1, 0, flags);
    // N6: g = h*W3
    gemm_v10<<<NGEMM, 256, 0, stream>>>(h, Wt3, g, 0, flags, ei, cnt, ell,
                                        W2, W3, Wt2);
    // N7: out = agg(g) + b3   (f32 out iff f32 inputs)
    agg_use_v10<<<SLICES * SLB, 256, 0, stream>>>(g, b3, cnt, ell2, d_out, 0, 1, flags);
}

// Round 11
// 197.068 us; speedup vs baseline: 1.1122x; 1.1122x over previous
//
#include <hip/hip_runtime.h>

typedef __attribute__((ext_vector_type(8))) short bf16x8;
typedef __attribute__((ext_vector_type(4))) float f32x4;

#define N_NODES 10000
#define N_EDGES 160000
#define FDIM    512
#define ELL     64
// gemm tile
#define BM 64
#define BN 128
#define BK 64
#define TM 157              // ceil(10000/64)
#define NGEMM (TM * 4)      // 628
#define NSCAT 625           // 625*256 = 160000
#define NTRAN 768           // 3 * 256 tiles of 32x32
#define NZERO 40            // 40*256 >= 10000
// agg slicing: slice pinned to XCD pair via blockIdx%8 heuristic
#define SLICES 4
#define SLW 128             // feats per slice (2.5 MB slice -> L2-resident)
#define SLB 2500            // node-groups per slice (4 nodes each)

__device__ __forceinline__ float bf2f(unsigned int u) {
    union { unsigned int i; float f; } v; v.i = u << 16; return v.f;
}
__device__ __forceinline__ unsigned short f2bf(float f) {
    union { float f; unsigned int u; } v; v.f = f;
    unsigned int u = v.u;
    unsigned int r = u + 0x7fffu + ((u >> 16) & 1u);
    return (unsigned short)(r >> 16);
}
__device__ __forceinline__ void gload_lds16(const void* g, void* l) {
    __builtin_amdgcn_global_load_lds(
        (const __attribute__((address_space(1))) unsigned int*)g,
        (__attribute__((address_space(3))) unsigned int*)l, 16, 0, 0);
}
__device__ __forceinline__ int wave_is_f32(const unsigned int* w) {
    unsigned int v = w[(size_t)(threadIdx.x & 63) * 1000];
    unsigned int ex = (v >> 7) & 0xFFu;
    unsigned long long inb = __ballot(ex >= 100u && ex <= 140u);
    return (__popcll(inb) >= 48) ? 0 : 1;
}

// ---------------- N1: transpose W1..3 || zero cnt || flags ---------------------
__global__ __launch_bounds__(256) void prep_v11(
        const void* __restrict__ x, const void* __restrict__ ei,
        const void* __restrict__ W1, const void* __restrict__ W2,
        const void* __restrict__ W3, unsigned short* __restrict__ Wt,
        int* __restrict__ cnt, int* __restrict__ flags) {
    int b = blockIdx.x, tid = threadIdx.x;
    if (b < NTRAN) {
        __shared__ unsigned short tile[32][33];
        int z = b >> 8, t = b & 255;
        const void* W = (z == 0) ? W1 : (z == 1) ? W2 : W3;
        unsigned short* outp = Wt + (size_t)z * FDIM * FDIM;
        int ff32 = wave_is_f32((const unsigned int*)W);
        int tx = tid & 31, ty = tid >> 5;              // 32 x 8
        int xcol = (t & 15) * 32 + tx;
        int y0 = (t >> 4) * 32 + ty;
        #pragma unroll
        for (int j = 0; j < 32; j += 8) {
            int idx = (y0 + j) * FDIM + xcol;
            tile[ty + j][tx] = ff32 ? f2bf(((const float*)W)[idx])
                                    : ((const unsigned short*)W)[idx];
        }
        __syncthreads();
        int x2 = (t >> 4) * 32 + tx;
        int y2 = (t & 15) * 32 + ty;
        #pragma unroll
        for (int j = 0; j < 32; j += 8)
            outp[(y2 + j) * FDIM + x2] = tile[tx][ty + j];
    } else if (b < NTRAN + NZERO) {
        int i = (b - NTRAN) * 256 + tid;
        if (i < N_NODES) cnt[i] = 0;
    } else {
        if (tid < 64) {
            const unsigned long long* e64 = (const unsigned long long*)ei;
            unsigned long long v = e64[(size_t)tid * 2500];
            unsigned long long big = __ballot(v > 0xFFFFFFFFull);
            const unsigned int* xw = (const unsigned int*)x;
            unsigned int w = xw[(size_t)tid * 1000];
            unsigned int ex = (w >> 7) & 0xFFu;
            unsigned long long inb = __ballot(ex >= 100u && ex <= 140u);
            if (tid == 0) {
                flags[0] = (big == 0ull) ? 1 : 0;          // int64?
                flags[1] = (__popcll(inb) >= 48) ? 0 : 1;  // f32?
            }
        }
    }
}

// ---------------- N2/N4/N6: swizzled MFMA GEMM (+opt ELL scatter tail) ---------
__global__ __launch_bounds__(256) void gemm_v11(
        const void* __restrict__ Ap, const unsigned short* __restrict__ Bt,
        unsigned short* __restrict__ C, int a_ext,
        const int* __restrict__ flags, const void* __restrict__ ei,
        int* __restrict__ cnt, int* __restrict__ ell) {
    __shared__ unsigned short As[BM * BK];
    __shared__ unsigned short Bs[BN * BK];
    if (blockIdx.x >= NGEMM) {
        int e = (blockIdx.x - NGEMM) * 256 + threadIdx.x;
        if (e < N_EDGES) {
            int r, c;
            if (flags[0]) {
                r = (int)((const long long*)ei)[e];
                c = (int)((const long long*)ei)[N_EDGES + e];
            } else {
                r = ((const int*)ei)[e];
                c = ((const int*)ei)[N_EDGES + e];
            }
            int slot = atomicAdd(&cnt[c], 1);
            if (slot < ELL) ell[(size_t)c * ELL + slot] = r;
        }
        return;
    }
    const int K = FDIM;
    const int af32 = a_ext ? flags[1] : 0;
    const int tid = threadIdx.x;
    const int t = blockIdx.x;
    const int bm = (t % TM) * BM, bn = (t / TM) * BN;
    const int lane = tid & 63, wv = tid >> 6;
    const int wm = (wv >> 1) * 32, wn = (wv & 1) * 64;
    const int lrow = lane & 15;
    const int tsl = lane >> 4;                        // 16B slot base (0..3)
    const int ksw = (lane & 7) ^ ((lane >> 3) & 7);   // swizzled stage k-slot
    const unsigned short* Abf = (const unsigned short*)Ap;
    f32x4 acc[2][4] = {};

    for (int k0 = 0; k0 < K; k0 += BK) {
        if (!af32) {
            #pragma unroll
            for (int j = 0; j < 2; ++j) {                 // A: 64 rows
                int r0 = wv * 16 + j * 8;
                int arow = bm + r0 + (lane >> 3);
                if (arow >= N_NODES) arow = N_NODES - 1;  // clamp: discarded
                gload_lds16(Abf + (size_t)arow * K + k0 + ksw * 8, &As[r0 * BK]);
            }
            #pragma unroll
            for (int j = 0; j < 4; ++j) {                 // B: 128 rows
                int r0 = wv * 32 + j * 8;
                gload_lds16(Bt + (size_t)(bn + r0 + (lane >> 3)) * K + k0 + ksw * 8,
                            &Bs[r0 * BK]);
            }
        } else {
            #pragma unroll
            for (int j = 0; j < 4; ++j) {
                int r0 = wv * 32 + j * 8;
                gload_lds16(Bt + (size_t)(bn + r0 + (lane >> 3)) * K + k0 + ksw * 8,
                            &Bs[r0 * BK]);
            }
            #pragma unroll
            for (int i = 0; i < 2; ++i) {                 // A f32 fallback
                int c = tid + i * 256;
                int row = c >> 3, sl = c & 7;
                int grow = bm + row;
                bf16x8 va = {};
                if (grow < N_NODES) {
                    const float* Af = (const float*)Ap + (size_t)grow * K + k0 + sl * 8;
                    f32x4 lo = *(const f32x4*)Af;
                    f32x4 hi = *(const f32x4*)(Af + 4);
                    #pragma unroll
                    for (int jj = 0; jj < 4; ++jj) {
                        va[jj]     = (short)f2bf(lo[jj]);
                        va[4 + jj] = (short)f2bf(hi[jj]);
                    }
                }
                *(bf16x8*)(&As[row * BK + ((sl ^ (row & 7)) * 8)]) = va;
            }
        }
        __syncthreads();
        #pragma unroll
        for (int half = 0; half < 2; ++half) {
            int ts = half * 4 + tsl;
            bf16x8 af[2], bfr[4];
            #pragma unroll
            for (int f = 0; f < 2; ++f) {
                int row = wm + f * 16 + lrow;
                af[f] = *(const bf16x8*)(&As[row * BK + ((ts ^ (lrow & 7)) * 8)]);
            }
            #pragma unroll
            for (int f = 0; f < 4; ++f) {
                int row = wn + f * 16 + lrow;
                bfr[f] = *(const bf16x8*)(&Bs[row * BK + ((ts ^ (lrow & 7)) * 8)]);
            }
            #pragma unroll
            for (int fm = 0; fm < 2; ++fm)
                #pragma unroll
                for (int fn = 0; fn < 4; ++fn)
                    acc[fm][fn] = __builtin_amdgcn_mfma_f32_16x16x32_bf16(
                        af[fm], bfr[fn], acc[fm][fn], 0, 0, 0);
        }
        __syncthreads();
    }

    int crow = (lane >> 4) * 4;
    int ccol = lane & 15;
    #pragma unroll
    for (int fm = 0; fm < 2; ++fm)
        #pragma unroll
        for (int fn = 0; fn < 4; ++fn)
            #pragma unroll
            for (int r = 0; r < 4; ++r) {
                int row = bm + wm + fm * 16 + crow + r;
                if (row < N_NODES)
                    C[(size_t)row * FDIM + bn + wn + fn * 16 + ccol] =
                        f2bf(acc[fm][fn][r]);
            }
}

// ---------------- N3/N5/N7: slice-blocked aggregation, XCD-pinned slices -------
// blockIdx%8 -> XCD (heuristic). XCDs {s, s+4} own slice s: each XCD's gather
// working set is one 2.5 MB slice -> L2-resident; L3 fill 20 MB/layer (was 80).
__global__ __launch_bounds__(256) void agg_sl_v11(
        const unsigned short* __restrict__ gin, const void* __restrict__ bias,
        const int* __restrict__ cnt, const int* __restrict__ ell,
        void* __restrict__ out, int relu, int out_ext,
        const int* __restrict__ flags) {
    const int wv = threadIdx.x >> 6, lane = threadIdx.x & 63;
    const int b = blockIdx.x;
    const int xcd = b & 7;
    const int idx = b >> 3;                        // 0..1249
    const int slice = xcd & 3;                     // XCD s, s+4 -> slice s
    const int ng = (xcd >> 2) * 1250 + idx;        // node group 0..2499
    const int i = ng * 4 + wv;
    const int fu = slice * (SLW / 2) + lane;       // uint index within row
    const unsigned int* g32 = (const unsigned int*)gin;   // row stride 256 uints
    int ci = cnt[i];
    int re = (ci > ELL) ? ELL : ci;
    const int* ep = ell + (size_t)i * ELL;
    int   srcl = (lane < re) ? ep[lane] : 0;
    int   cl   = (lane < re) ? cnt[srcl] : 0;
    float wl   = rsqrtf((float)(cl + 1) * (float)(ci + 1));
    float a0 = 0.f, a1 = 0.f;
    int j = 0;
    for (; j + 8 <= re; j += 8) {
        int s0 = __shfl(srcl, j);     float w0 = __shfl(wl, j);
        int s1 = __shfl(srcl, j + 1); float w1 = __shfl(wl, j + 1);
        int s2 = __shfl(srcl, j + 2); float w2 = __shfl(wl, j + 2);
        int s3 = __shfl(srcl, j + 3); float w3 = __shfl(wl, j + 3);
        int s4 = __shfl(srcl, j + 4); float w4 = __shfl(wl, j + 4);
        int s5 = __shfl(srcl, j + 5); float w5 = __shfl(wl, j + 5);
        int s6 = __shfl(srcl, j + 6); float w6 = __shfl(wl, j + 6);
        int s7 = __shfl(srcl, j + 7); float w7 = __shfl(wl, j + 7);
        unsigned int v0 = g32[(size_t)s0 * 256 + fu];
        unsigned int v1 = g32[(size_t)s1 * 256 + fu];
        unsigned int v2 = g32[(size_t)s2 * 256 + fu];
        unsigned int v3 = g32[(size_t)s3 * 256 + fu];
        unsigned int v4 = g32[(size_t)s4 * 256 + fu];
        unsigned int v5 = g32[(size_t)s5 * 256 + fu];
        unsigned int v6 = g32[(size_t)s6 * 256 + fu];
        unsigned int v7 = g32[(size_t)s7 * 256 + fu];
        a0 += w0 * bf2f(v0 & 0xffffu); a1 += w0 * bf2f(v0 >> 16);
        a0 += w1 * bf2f(v1 & 0xffffu); a1 += w1 * bf2f(v1 >> 16);
        a0 += w2 * bf2f(v2 & 0xffffu); a1 += w2 * bf2f(v2 >> 16);
        a0 += w3 * bf2f(v3 & 0xffffu); a1 += w3 * bf2f(v3 >> 16);
        a0 += w4 * bf2f(v4 & 0xffffu); a1 += w4 * bf2f(v4 >> 16);
        a0 += w5 * bf2f(v5 & 0xffffu); a1 += w5 * bf2f(v5 >> 16);
        a0 += w6 * bf2f(v6 & 0xffffu); a1 += w6 * bf2f(v6 >> 16);
        a0 += w7 * bf2f(v7 & 0xffffu); a1 += w7 * bf2f(v7 >> 16);
    }
    for (; j < re; ++j) {
        int s = __shfl(srcl, j); float w = __shfl(wl, j);
        unsigned int v = g32[(size_t)s * 256 + fu];
        a0 += w * bf2f(v & 0xffffu); a1 += w * bf2f(v >> 16);
    }
    float wself = 1.0f / (float)(ci + 1);
    unsigned int vs = g32[(size_t)i * 256 + fu];
    a0 += wself * bf2f(vs & 0xffffu); a1 += wself * bf2f(vs >> 16);
    int ff32 = flags[1];
    if (ff32) {
        const float* B = (const float*)bias + fu * 2;
        a0 += B[0]; a1 += B[1];
    } else {
        unsigned int bb = ((const unsigned int*)bias)[fu];
        a0 += bf2f(bb & 0xffffu); a1 += bf2f(bb >> 16);
    }
    if (relu) { a0 = fmaxf(a0, 0.f); a1 = fmaxf(a1, 0.f); }
    if (out_ext && ff32) {
        float2 o = {a0, a1};
        *(float2*)((float*)out + (size_t)i * FDIM + fu * 2) = o;
    } else {
        unsigned int o = (unsigned int)f2bf(a0) | ((unsigned int)f2bf(a1) << 16);
        ((unsigned int*)out)[(size_t)i * 256 + fu] = o;
    }
}

// ---------------- launcher ------------------------------------------------------
extern "C" void kernel_launch(void* const* d_in, const int* in_sizes, int n_in,
                              void* d_out, int out_size, void* d_ws, size_t ws_size,
                              hipStream_t stream) {
    (void)in_sizes; (void)n_in; (void)out_size; (void)ws_size;
    const void* x  = d_in[0];
    const void* ei = d_in[1];
    const void* W1 = d_in[2];
    const void* b1 = d_in[3];
    const void* W2 = d_in[4];
    const void* b2 = d_in[5];
    const void* W3 = d_in[6];
    const void* b3 = d_in[7];

    char* p = (char*)d_ws;
    auto alloc = [&](size_t bytes) -> void* {
        void* r = (void*)p;
        p += (bytes + 255) & ~(size_t)255;
        return r;
    };
    int*  flags = (int*) alloc(16);
    int*  cnt   = (int*) alloc((size_t)N_NODES * 4);
    int*  ell   = (int*) alloc((size_t)N_NODES * ELL * 4);
    unsigned short* Wt = (unsigned short*)alloc((size_t)3 * FDIM * FDIM * 2);
    unsigned short* g  = (unsigned short*)alloc((size_t)N_NODES * FDIM * 2);
    // ws use ~14.4 MB

    unsigned short* Wt1 = Wt;
    unsigned short* Wt2 = Wt + (size_t)FDIM * FDIM;
    unsigned short* Wt3 = Wt + (size_t)2 * FDIM * FDIM;
    unsigned short* h   = (unsigned short*)d_out;       // bf16 scratch in d_out

    // N1: transpose + zero cnt + flags
    prep_v11<<<NTRAN + NZERO + 1, 256, 0, stream>>>(x, ei, W1, W2, W3, Wt, cnt, flags);
    // N2: g = x*W1  (+ ELL scatter builds cnt/ell)
    gemm_v11<<<NGEMM + NSCAT, 256, 0, stream>>>(x, Wt1, g, 1, flags, ei, cnt, ell);
    // N3: h = relu(agg(g) + b1)
    agg_sl_v11<<<SLICES * SLB, 256, 0, stream>>>(g, b1, cnt, ell, h, 1, 0, flags);
    // N4: g = h*W2
    gemm_v11<<<NGEMM, 256, 0, stream>>>(h, Wt2, g, 0, flags, ei, cnt, ell);
    // N5: h = relu(agg(g) + b2)
    agg_sl_v11<<<SLICES * SLB, 256, 0, stream>>>(g, b2, cnt, ell, h, 1, 0, flags);
    // N6: g = h*W3
    gemm_v11<<<NGEMM, 256, 0, stream>>>(h, Wt3, g, 0, flags, ei, cnt, ell);
    // N7: out = agg(g) + b3   (f32 out iff f32 inputs)
    agg_sl_v11<<<SLICES * SLB, 256, 0, stream>>>(g, b3, cnt, ell, d_out, 0, 1, flags);
}